// Round 4
// baseline (11745.488 us; speedup 1.0000x reference)
//
#include <hip/hip_runtime.h>
#include <hip/hip_bf16.h>

#define VOCAB  32000
#define EMBED  256
#define HIDDEN 1024
#define G4     4096
#define BATCH  64
#define SEQ    256

// ---------------------------------------------------------------------------
// Kernel 1: xgT[t][n][b] = b_ih[n] + b_hh[n] + sum_e embed[x[b,t]][e] * W_ih[n][e]
// As = W_ih rows (n), Bs = gathered emb rows (b). acc[i][j]: i->n, j->b so the
// store xgT[t][n][b] is coalesced over tx (b fastest).
// ---------------------------------------------------------------------------
__global__ __launch_bounds__(256) void lstm_xgates(
    const int* __restrict__ x,           // [B, T]
    const float* __restrict__ emb,       // [VOCAB, EMBED]
    const float* __restrict__ W_ih,      // [G4, EMBED]
    const float* __restrict__ b_ih,
    const float* __restrict__ b_hh,
    float* __restrict__ xgT)             // [T, G4, B]
{
    const int t   = blockIdx.y;
    const int n0  = blockIdx.x * 64;
    const int tid = threadIdx.x;
    const int ty  = tid >> 4;
    const int tx  = tid & 15;

    __shared__ float As[64][36];   // W_ih rows (n)
    __shared__ float Bs[64][36];   // emb rows (b)
    __shared__ int   ridx[64];

    if (tid < 64) ridx[tid] = x[tid * SEQ + t];
    __syncthreads();

    float acc[4][4];
#pragma unroll
    for (int i = 0; i < 4; ++i)
#pragma unroll
        for (int j = 0; j < 4; ++j) acc[i][j] = 0.f;

    const int lr = tid >> 2;          // 0..63
    const int lc = (tid & 3) * 8;     // 0,8,16,24
    const float* abase = W_ih + (long)(n0 + lr) * EMBED + lc;
    const float* bbase = emb + (long)ridx[lr] * EMBED + lc;

    for (int k0 = 0; k0 < EMBED; k0 += 32) {
        *(float4*)&As[lr][lc]     = *(const float4*)(abase + k0);
        *(float4*)&As[lr][lc + 4] = *(const float4*)(abase + k0 + 4);
        *(float4*)&Bs[lr][lc]     = *(const float4*)(bbase + k0);
        *(float4*)&Bs[lr][lc + 4] = *(const float4*)(bbase + k0 + 4);
        __syncthreads();

#pragma unroll
        for (int kk = 0; kk < 32; kk += 4) {
            float4 av[4], bv[4];
#pragma unroll
            for (int i = 0; i < 4; ++i) av[i] = *(const float4*)&As[ty + 16 * i][kk];
#pragma unroll
            for (int j = 0; j < 4; ++j) bv[j] = *(const float4*)&Bs[tx + 16 * j][kk];
#pragma unroll
            for (int i = 0; i < 4; ++i)
#pragma unroll
                for (int j = 0; j < 4; ++j)
                    acc[i][j] += av[i].x * bv[j].x + av[i].y * bv[j].y
                               + av[i].z * bv[j].z + av[i].w * bv[j].w;
        }
        __syncthreads();
    }

#pragma unroll
    for (int i = 0; i < 4; ++i) {
        const int n = n0 + ty + 16 * i;
        const float bias = b_ih[n] + b_hh[n];
#pragma unroll
        for (int j = 0; j < 4; ++j) {
            const int b = tx + 16 * j;
            xgT[((long)t * G4 + n) * BATCH + b] = acc[i][j] + bias;
        }
    }
}

// ---------------------------------------------------------------------------
// Zero-init hT4 (hA) and cT4. (ws is poisoned 0xAA before every call.)
// ---------------------------------------------------------------------------
__global__ void lstm_init(float* __restrict__ h0, float* __restrict__ c)
{
    const int i = blockIdx.x * blockDim.x + threadIdx.x;
    if (i < BATCH * HIDDEN) { h0[i] = 0.f; c[i] = 0.f; }
}

// ---------------------------------------------------------------------------
// Kernel 2 (x256): one fused LSTM step.
//   Block (512 thr, 8 waves) owns rows {g*1024 + tile*4 + jj : g,jj in 0..3}
//   (16 rows) x all 64 b. lane = batch b. Wave w owns k-eighth [w*128,+128)
//   (split-K across 8 waves -> 2 waves/SIMD for latency co-scheduling).
//   h from LDS (one ds_read_b128 = 4 k feeds 64 FMAs); W_hh via wave-uniform
//   reads (s_load_dwordx4, SMEM pipe; v_fmac v,s,v).
//   LDS: 2 x 32 KB double-buffered h stage (reg-staged); Zs overlays buf0.
//   Gate phase fused: wave w<4 computes jj=w. h layout hT4[k/4][b][4].
// ---------------------------------------------------------------------------
__global__ __launch_bounds__(512) void lstm_step(
    const float* __restrict__ W_hh,    // [4096][1024]
    const float* __restrict__ xgT_t,   // [4096][64] slice for this t
    const float* __restrict__ h_in,    // hT4: [256][64][4]
    float* __restrict__ h_out,         // hT4
    float* __restrict__ c)             // cT4: [256][64][4]
{
    const int tile = blockIdx.x;                                // 0..255
    const int tid  = threadIdx.x;                               // 0..511
    const int w    = __builtin_amdgcn_readfirstlane(tid >> 6);  // wave id 0..7
    const int b    = tid & 63;                                  // lane = batch

    __shared__ float4 buf0[2048];   // 32 KB: [32 slots][64 b], slot = w + 8i
    __shared__ float4 buf1[2048];

    const float4* hin4 = (const float4*)h_in;
    const float4* W4   = (const float4*)W_hh;   // W4[row*256 + k4]

    float acc[16];
#pragma unroll
    for (int r = 0; r < 16; ++r) acc[r] = 0.f;

    // prefetch gate-phase xg operands early (waves 0..3 only)
    float xgv[4] = {0.f, 0.f, 0.f, 0.f};
    if (w < 4) {
#pragma unroll
        for (int g = 0; g < 4; ++g)
            xgv[g] = xgT_t[((long)(g << 10) + (tile << 2) + w) * BATCH + b];
    }

    float4 st[4];

    // ---- preload sub 0 into buf0 ----
#pragma unroll
    for (int i = 0; i < 4; ++i) {
        const int slot = w + 8 * i;                    // 0..31
        const int k4g  = (slot >> 2) * 32 + (slot & 3);
        st[i] = hin4[k4g * 64 + b];
    }
#pragma unroll
    for (int i = 0; i < 4; ++i) buf0[(w + 8 * i) * 64 + b] = st[i];
    __syncthreads();

    // ---- K loop: 8 subs of 16 k (4 k4) per wave-eighth ----
    for (int s = 0; s < 8; ++s) {
        const float4* cur = (s & 1) ? buf1 : buf0;

        if (s < 7) {
            // issue next-sub global loads (hidden under compute)
#pragma unroll
            for (int i = 0; i < 4; ++i) {
                const int slot = w + 8 * i;
                const int k4g  = (slot >> 2) * 32 + (s + 1) * 4 + (slot & 3);
                st[i] = hin4[k4g * 64 + b];
            }
        }

        // batch the LDS reads up-front (static indices -> VGPRs, one lgkm drain)
        float4 h4v[4];
#pragma unroll
        for (int kl = 0; kl < 4; ++kl) h4v[kl] = cur[(w * 4 + kl) * 64 + b];

#pragma unroll
        for (int kl = 0; kl < 4; ++kl) {
            const float4 h4  = h4v[kl];
            const int    k4g = w * 32 + s * 4 + kl;         // uniform
#pragma unroll
            for (int r = 0; r < 16; ++r) {
                const int row = ((r >> 2) << 10) + (tile << 2) + (r & 3);  // uniform
                const float4 wv = W4[(long)row * 256 + k4g];               // s_load
                acc[r] = fmaf(wv.x, h4.x, acc[r]);
                acc[r] = fmaf(wv.y, h4.y, acc[r]);
                acc[r] = fmaf(wv.z, h4.z, acc[r]);
                acc[r] = fmaf(wv.w, h4.w, acc[r]);
            }
        }

        if (s < 7) {
            __syncthreads();
            float4* nxt = (s & 1) ? buf0 : buf1;
#pragma unroll
            for (int i = 0; i < 4; ++i) nxt[(w + 8 * i) * 64 + b] = st[i];
            __syncthreads();
        }
    }

    // ---- cross-wave split-K reduce: Zs overlays buf0 (last compute used buf1) ----
    __syncthreads();
    float* Zs = (float*)buf0;   // [8 waves][16 r][64 b] = 32 KB
#pragma unroll
    for (int r = 0; r < 16; ++r) Zs[(w * 16 + r) * 64 + b] = acc[r];
    __syncthreads();

    // ---- fused gate phase: wave w<4 handles jj = w ----
    if (w < 4) {
        const int jj = w;
        float z[4];
#pragma unroll
        for (int g = 0; g < 4; ++g) {
            float sum = xgv[g];
#pragma unroll
            for (int wp = 0; wp < 8; ++wp)
                sum += Zs[(wp * 16 + g * 4 + jj) * 64 + b];
            z[g] = sum;
        }
        const float ig = 1.f / (1.f + __expf(-z[0]));
        const float fg = 1.f / (1.f + __expf(-z[1]));
        const float gg = tanhf(z[2]);
        const float og = 1.f / (1.f + __expf(-z[3]));
        float* cp = c + (tile * 64 + b) * 4 + jj;
        const float cn = fg * (*cp) + ig * gg;
        *cp = cn;
        h_out[(tile * 64 + b) * 4 + jj] = og * tanhf(cn);
    }
}

// ---------------------------------------------------------------------------
// Kernel 3: out[b][v] = fc_b[v] + sum_k h[b][k] * fc_W[v][k]
// h read from hT4 layout. 64b x 64v tile, 4x4 micro.
// ---------------------------------------------------------------------------
__global__ __launch_bounds__(256) void lstm_fc(
    const float* __restrict__ h,       // hT4: [256][64][4]
    const float* __restrict__ fc_W,    // [VOCAB, H]
    const float* __restrict__ fc_b,    // [VOCAB]
    float* __restrict__ out)           // [B, VOCAB]
{
    const int v0  = blockIdx.x * 64;
    const int tid = threadIdx.x;
    const int ty  = tid >> 4;
    const int tx  = tid & 15;

    __shared__ float Hs[64][36];
    __shared__ float Ws[64][36];

    float acc[4][4];
#pragma unroll
    for (int i = 0; i < 4; ++i)
#pragma unroll
        for (int j = 0; j < 4; ++j) acc[i][j] = 0.f;

    const int lr = tid >> 2;
    const int lc = (tid & 3) * 8;
    const float4* h4 = (const float4*)h;
    const float* wbase = fc_W + (long)(v0 + lr) * HIDDEN + lc;

    for (int k0 = 0; k0 < HIDDEN; k0 += 32) {
        *(float4*)&Hs[lr][lc]     = h4[((k0 + lc) >> 2) * 64 + lr];
        *(float4*)&Hs[lr][lc + 4] = h4[((k0 + lc + 4) >> 2) * 64 + lr];
        *(float4*)&Ws[lr][lc]     = *(const float4*)(wbase + k0);
        *(float4*)&Ws[lr][lc + 4] = *(const float4*)(wbase + k0 + 4);
        __syncthreads();

#pragma unroll
        for (int kk = 0; kk < 32; kk += 4) {
            float4 hv[4], wv[4];
#pragma unroll
            for (int i = 0; i < 4; ++i) hv[i] = *(const float4*)&Hs[ty + 16 * i][kk];
#pragma unroll
            for (int j = 0; j < 4; ++j) wv[j] = *(const float4*)&Ws[tx + 16 * j][kk];
#pragma unroll
            for (int i = 0; i < 4; ++i)
#pragma unroll
                for (int j = 0; j < 4; ++j)
                    acc[i][j] += hv[i].x * wv[j].x + hv[i].y * wv[j].y
                               + hv[i].z * wv[j].z + hv[i].w * wv[j].w;
        }
        __syncthreads();
    }

#pragma unroll
    for (int j = 0; j < 4; ++j) {
        const int v = v0 + tx + 16 * j;
        const float bias = fc_b[v];
#pragma unroll
        for (int i = 0; i < 4; ++i) {
            const int b = ty + 16 * i;
            out[(long)b * VOCAB + v] = acc[i][j] + bias;
        }
    }
}

// ---------------------------------------------------------------------------
extern "C" void kernel_launch(void* const* d_in, const int* in_sizes, int n_in,
                              void* d_out, int out_size, void* d_ws, size_t ws_size,
                              hipStream_t stream)
{
    const int*   x     = (const int*)d_in[0];
    const float* emb   = (const float*)d_in[1];
    const float* W_ih  = (const float*)d_in[2];
    const float* W_hh  = (const float*)d_in[3];
    const float* b_ih  = (const float*)d_in[4];
    const float* b_hh  = (const float*)d_in[5];
    const float* fc_W  = (const float*)d_in[6];
    const float* fc_b  = (const float*)d_in[7];
    float* out = (float*)d_out;

    // workspace layout (f32): xgT [T][4H][B] | hA | hB | c   (~257 MB)
    float* xgT = (float*)d_ws;
    float* hA  = xgT + (long)SEQ * G4 * BATCH;   // 67,108,864 floats in
    float* hB  = hA + BATCH * HIDDEN;
    float* c   = hB + BATCH * HIDDEN;

    lstm_xgates<<<dim3(G4 / 64, SEQ), 256, 0, stream>>>(x, emb, W_ih, b_ih, b_hh, xgT);
    lstm_init<<<dim3(BATCH * HIDDEN / 256), 256, 0, stream>>>(hA, c);

    float* hb[2] = {hA, hB};
    for (int t = 0; t < SEQ; ++t) {
        lstm_step<<<dim3(HIDDEN / 4), 512, 0, stream>>>(
            W_hh, xgT + (long)t * G4 * BATCH, hb[t & 1], hb[(t + 1) & 1], c);
    }
    // T even -> final h is in hA
    lstm_fc<<<dim3(VOCAB / 64), 256, 0, stream>>>(hA, fc_W, fc_b, out);
}

// Round 5
// 4205.191 us; speedup vs baseline: 2.7931x; 2.7931x over previous
//
#include <hip/hip_runtime.h>
#include <hip/hip_bf16.h>

#define VOCAB  32000
#define EMBED  256
#define HIDDEN 1024
#define G4     4096
#define BATCH  64
#define SEQ    256

// ---------------------------------------------------------------------------
// Kernel 1: xgT[t][n][b] = b_ih[n] + b_hh[n] + sum_e embed[x[b,t]][e] * W_ih[n][e]
// (unchanged from round 1/2 — keep bisectable)
// ---------------------------------------------------------------------------
__global__ __launch_bounds__(256) void lstm_xgates(
    const int* __restrict__ x,           // [B, T]
    const float* __restrict__ emb,       // [VOCAB, EMBED]
    const float* __restrict__ W_ih,      // [G4, EMBED]
    const float* __restrict__ b_ih,
    const float* __restrict__ b_hh,
    float* __restrict__ xgT)             // [T, G4, B]
{
    const int t   = blockIdx.y;
    const int n0  = blockIdx.x * 64;
    const int tid = threadIdx.x;
    const int ty  = tid >> 4;
    const int tx  = tid & 15;

    __shared__ float As[64][36];   // W_ih rows (n)
    __shared__ float Bs[64][36];   // emb rows (b)
    __shared__ int   ridx[64];

    if (tid < 64) ridx[tid] = x[tid * SEQ + t];
    __syncthreads();

    float acc[4][4];
#pragma unroll
    for (int i = 0; i < 4; ++i)
#pragma unroll
        for (int j = 0; j < 4; ++j) acc[i][j] = 0.f;

    const int lr = tid >> 2;          // 0..63
    const int lc = (tid & 3) * 8;     // 0,8,16,24
    const float* abase = W_ih + (long)(n0 + lr) * EMBED + lc;
    const float* bbase = emb + (long)ridx[lr] * EMBED + lc;

    for (int k0 = 0; k0 < EMBED; k0 += 32) {
        *(float4*)&As[lr][lc]     = *(const float4*)(abase + k0);
        *(float4*)&As[lr][lc + 4] = *(const float4*)(abase + k0 + 4);
        *(float4*)&Bs[lr][lc]     = *(const float4*)(bbase + k0);
        *(float4*)&Bs[lr][lc + 4] = *(const float4*)(bbase + k0 + 4);
        __syncthreads();

#pragma unroll
        for (int kk = 0; kk < 32; kk += 4) {
            float4 av[4], bv[4];
#pragma unroll
            for (int i = 0; i < 4; ++i) av[i] = *(const float4*)&As[ty + 16 * i][kk];
#pragma unroll
            for (int j = 0; j < 4; ++j) bv[j] = *(const float4*)&Bs[tx + 16 * j][kk];
#pragma unroll
            for (int i = 0; i < 4; ++i)
#pragma unroll
                for (int j = 0; j < 4; ++j)
                    acc[i][j] += av[i].x * bv[j].x + av[i].y * bv[j].y
                               + av[i].z * bv[j].z + av[i].w * bv[j].w;
        }
        __syncthreads();
    }

#pragma unroll
    for (int i = 0; i < 4; ++i) {
        const int n = n0 + ty + 16 * i;
        const float bias = b_ih[n] + b_hh[n];
#pragma unroll
        for (int j = 0; j < 4; ++j) {
            const int b = tx + 16 * j;
            xgT[((long)t * G4 + n) * BATCH + b] = acc[i][j] + bias;
        }
    }
}

// ---------------------------------------------------------------------------
__global__ void lstm_init(float* __restrict__ h0, float* __restrict__ c)
{
    const int i = blockIdx.x * blockDim.x + threadIdx.x;
    if (i < BATCH * HIDDEN) { h0[i] = 0.f; c[i] = 0.f; }
}

// ---------------------------------------------------------------------------
// Kernel 2 (x256): one fused LSTM step — v3: LDS-broadcast W, L2-direct h.
//   Block (512 thr, 8 waves) owns 16 rows {g*1024 + tile*4 + jj} x all 64 b.
//   lane = b. Wave w owns k-eighth [w*128, +128) (split-K, Zs reduce).
//   W-tile 16x1024 f32 = 64 KB staged to LDS once/step; ALL W reads are
//   lane-uniform ds_read_b128 -> hardware broadcast (conflict-free, cheap).
//   h is NEVER staged: coalesced global float4 loads from hT4[k4][b],
//   double-buffered in registers (h = 256 KB, L2-resident per XCD).
//   2 barriers/step. Gates fused (wave w<4 handles jj=w).
// ---------------------------------------------------------------------------
__global__ __launch_bounds__(512, 1) void lstm_step(
    const float* __restrict__ W_hh,    // [4096][1024]
    const float* __restrict__ xgT_t,   // [4096][64] slice for this t
    const float* __restrict__ h_in,    // hT4: [256][64][4]
    float* __restrict__ h_out,         // hT4
    float* __restrict__ c)             // cT4: [256][64][4]
{
    const int tile = blockIdx.x;                                // 0..255
    const int tid  = threadIdx.x;                               // 0..511
    const int w    = __builtin_amdgcn_readfirstlane(tid >> 6);  // wave id 0..7
    const int b    = tid & 63;                                  // lane = batch

    __shared__ float Wlds[16][1024];    // 64 KB, linear (reads are broadcast)
    __shared__ float Zs[8][16][64];     // 32 KB split-K partials

    const float4* hin4 = (const float4*)h_in;
    const float4* W4   = (const float4*)W_hh;    // W4[row*256 + k4]
    float4*       WL4  = (float4*)&Wlds[0][0];   // flat f4 view, 4096 entries

    // ---- issue W-tile stage loads (16 rows x 256 f4 = 4096 f4, 8/thread) ----
    float4 wst[8];
#pragma unroll
    for (int i = 0; i < 8; ++i) {
        const int f     = tid + i * 512;          // flat f4 index
        const int row16 = f >> 8;                 // 0..15
        const int k4i   = f & 255;
        const int grow  = ((row16 >> 2) << 10) + (tile << 2) + (row16 & 3);
        wst[i] = W4[(long)grow * 256 + k4i];
    }

    // ---- prefetch gate-phase xg operands (waves 0..3) ----
    float xgv[4] = {0.f, 0.f, 0.f, 0.f};
    if (w < 4) {
#pragma unroll
        for (int g = 0; g < 4; ++g)
            xgv[g] = xgT_t[((long)(g << 10) + (tile << 2) + w) * BATCH + b];
    }

    // ---- prefetch h sub 0 (4 k4 per sub, 8 subs cover the k-eighth) ----
    float4 stc[4], stn[4];
#pragma unroll
    for (int i = 0; i < 4; ++i)
        stc[i] = hin4[(w * 32 + i) * 64 + b];

    // ---- write W stage to LDS, one barrier ----
#pragma unroll
    for (int i = 0; i < 8; ++i) WL4[tid + i * 512] = wst[i];
    __syncthreads();

    float acc[16];
#pragma unroll
    for (int r = 0; r < 16; ++r) acc[r] = 0.f;

    // ---- K loop: 8 subs x 4 k4; W via LDS broadcast, h in regs ----
#pragma unroll
    for (int s = 0; s < 8; ++s) {
        if (s < 7) {
#pragma unroll
            for (int i = 0; i < 4; ++i)
                stn[i] = hin4[(w * 32 + (s + 1) * 4 + i) * 64 + b];
        }
#pragma unroll
        for (int kk = 0; kk < 4; ++kk) {
            const float4 h4 = stc[kk];
            const int    k4 = w * 32 + s * 4 + kk;   // wave-uniform
#pragma unroll
            for (int r = 0; r < 16; ++r) {
                // lane-uniform address -> LDS broadcast read (conflict-free)
                const float4 wv = *(const float4*)&Wlds[r][k4 * 4];
                acc[r] = fmaf(wv.x, h4.x, acc[r]);
                acc[r] = fmaf(wv.y, h4.y, acc[r]);
                acc[r] = fmaf(wv.z, h4.z, acc[r]);
                acc[r] = fmaf(wv.w, h4.w, acc[r]);
            }
        }
#pragma unroll
        for (int i = 0; i < 4; ++i) stc[i] = stn[i];
    }

    // ---- split-K reduce via Zs ----
#pragma unroll
    for (int r = 0; r < 16; ++r) Zs[w][r][b] = acc[r];
    __syncthreads();

    // ---- fused gate phase: wave w<4 handles jj = w ----
    if (w < 4) {
        const int jj = w;
        float z[4];
#pragma unroll
        for (int g = 0; g < 4; ++g) {
            float sum = xgv[g];
#pragma unroll
            for (int wp = 0; wp < 8; ++wp)
                sum += Zs[wp][g * 4 + jj][b];
            z[g] = sum;
        }
        const float ig = 1.f / (1.f + __expf(-z[0]));
        const float fg = 1.f / (1.f + __expf(-z[1]));
        const float gg = tanhf(z[2]);
        const float og = 1.f / (1.f + __expf(-z[3]));
        float* cp = c + (tile * 64 + b) * 4 + jj;
        const float cn = fg * (*cp) + ig * gg;
        *cp = cn;
        h_out[(tile * 64 + b) * 4 + jj] = og * tanhf(cn);
    }
}

// ---------------------------------------------------------------------------
// Kernel 3: out[b][v] = fc_b[v] + sum_k h[b][k] * fc_W[v][k]  (unchanged)
// ---------------------------------------------------------------------------
__global__ __launch_bounds__(256) void lstm_fc(
    const float* __restrict__ h,       // hT4: [256][64][4]
    const float* __restrict__ fc_W,    // [VOCAB, H]
    const float* __restrict__ fc_b,    // [VOCAB]
    float* __restrict__ out)           // [B, VOCAB]
{
    const int v0  = blockIdx.x * 64;
    const int tid = threadIdx.x;
    const int ty  = tid >> 4;
    const int tx  = tid & 15;

    __shared__ float Hs[64][36];
    __shared__ float Ws[64][36];

    float acc[4][4];
#pragma unroll
    for (int i = 0; i < 4; ++i)
#pragma unroll
        for (int j = 0; j < 4; ++j) acc[i][j] = 0.f;

    const int lr = tid >> 2;
    const int lc = (tid & 3) * 8;
    const float4* h4 = (const float4*)h;
    const float* wbase = fc_W + (long)(v0 + lr) * HIDDEN + lc;

    for (int k0 = 0; k0 < HIDDEN; k0 += 32) {
        *(float4*)&Hs[lr][lc]     = h4[((k0 + lc) >> 2) * 64 + lr];
        *(float4*)&Hs[lr][lc + 4] = h4[((k0 + lc + 4) >> 2) * 64 + lr];
        *(float4*)&Ws[lr][lc]     = *(const float4*)(wbase + k0);
        *(float4*)&Ws[lr][lc + 4] = *(const float4*)(wbase + k0 + 4);
        __syncthreads();

#pragma unroll
        for (int kk = 0; kk < 32; kk += 4) {
            float4 hv[4], wv[4];
#pragma unroll
            for (int i = 0; i < 4; ++i) hv[i] = *(const float4*)&Hs[ty + 16 * i][kk];
#pragma unroll
            for (int j = 0; j < 4; ++j) wv[j] = *(const float4*)&Ws[tx + 16 * j][kk];
#pragma unroll
            for (int i = 0; i < 4; ++i)
#pragma unroll
                for (int j = 0; j < 4; ++j)
                    acc[i][j] += hv[i].x * wv[j].x + hv[i].y * wv[j].y
                               + hv[i].z * wv[j].z + hv[i].w * wv[j].w;
        }
        __syncthreads();
    }

#pragma unroll
    for (int j = 0; j < 4; ++j) {
        const int v = v0 + tx + 16 * j;
        const float bias = fc_b[v];
#pragma unroll
        for (int i = 0; i < 4; ++i) {
            const int b = ty + 16 * i;
            out[(long)b * VOCAB + v] = acc[i][j] + bias;
        }
    }
}

// ---------------------------------------------------------------------------
extern "C" void kernel_launch(void* const* d_in, const int* in_sizes, int n_in,
                              void* d_out, int out_size, void* d_ws, size_t ws_size,
                              hipStream_t stream)
{
    const int*   x     = (const int*)d_in[0];
    const float* emb   = (const float*)d_in[1];
    const float* W_ih  = (const float*)d_in[2];
    const float* W_hh  = (const float*)d_in[3];
    const float* b_ih  = (const float*)d_in[4];
    const float* b_hh  = (const float*)d_in[5];
    const float* fc_W  = (const float*)d_in[6];
    const float* fc_b  = (const float*)d_in[7];
    float* out = (float*)d_out;

    // workspace layout (f32): xgT [T][4H][B] | hA | hB | c   (~257 MB)
    float* xgT = (float*)d_ws;
    float* hA  = xgT + (long)SEQ * G4 * BATCH;   // 67,108,864 floats in
    float* hB  = hA + BATCH * HIDDEN;
    float* c   = hB + BATCH * HIDDEN;

    lstm_xgates<<<dim3(G4 / 64, SEQ), 256, 0, stream>>>(x, emb, W_ih, b_ih, b_hh, xgT);
    lstm_init<<<dim3(BATCH * HIDDEN / 256), 256, 0, stream>>>(hA, c);

    float* hb[2] = {hA, hB};
    for (int t = 0; t < SEQ; ++t) {
        lstm_step<<<dim3(HIDDEN / 4), 512, 0, stream>>>(
            W_hh, xgT + (long)t * G4 * BATCH, hb[t & 1], hb[(t + 1) & 1], c);
    }
    // T even -> final h is in hA
    lstm_fc<<<dim3(VOCAB / 64), 256, 0, stream>>>(hA, fc_W, fc_b, out);
}

// Round 8
// 4005.658 us; speedup vs baseline: 2.9322x; 1.0498x over previous
//
#include <hip/hip_runtime.h>
#include <hip/hip_bf16.h>

#define VOCAB  32000
#define EMBED  256
#define HIDDEN 1024
#define G4     4096
#define BATCH  64
#define SEQ    256

typedef short s16x8 __attribute__((ext_vector_type(8)));
typedef float f32x4 __attribute__((ext_vector_type(4)));

static __device__ __forceinline__ unsigned short f2bf(float f) {
    unsigned u = __float_as_uint(f);
    unsigned r = (u + 0x7fffu + ((u >> 16) & 1u)) >> 16;   // RNE
    return (unsigned short)r;
}
static __device__ __forceinline__ float bf2f(unsigned short s) {
    return __uint_as_float(((unsigned)s) << 16);
}

// ---------------------------------------------------------------------------
// Kernel 0: W_hh -> fragment-ready split-bf16 layout.
// Wf[tile(256)][kstep(32)][part(2)][lane(64)][e(8)] shorts, 16 MB.
// Element = part(W_hh[grow][k]) with r=lane&15, g=lane>>4,
//   grow = (r>>2)*1024 + tile*4 + (r&3), k = kstep*32 + g*8 + e.
// Same slot->k map (g*8+e) is used by the step kernel's h loads -> the MFMA
// dot product is invariant to the true HW k-slot order (A/B symmetric).
// ---------------------------------------------------------------------------
__global__ __launch_bounds__(256) void lstm_wprep(
    const float* __restrict__ W_hh,        // [4096][1024]
    unsigned short* __restrict__ Wf)
{
    const int tile = blockIdx.x;           // 0..255
    const int ky   = blockIdx.y;           // 0..7
    const int tid  = threadIdx.x;
    const int wv   = tid >> 6;             // 0..3
    const int lane = tid & 63;
    const int ks   = ky * 4 + wv;          // 0..31
    const int r    = lane & 15;
    const int g    = lane >> 4;
    const int grow = (r >> 2) * 1024 + tile * 4 + (r & 3);
    const float* src = W_hh + (long)grow * 1024 + ks * 32 + g * 8;

    s16x8 hi, lo;
#pragma unroll
    for (int e = 0; e < 8; ++e) {
        const float v = src[e];
        const unsigned short h = f2bf(v);
        hi[e] = (short)h;
        lo[e] = (short)f2bf(v - bf2f(h));
    }
    s16x8* dst = (s16x8*)(Wf + ((long)(tile * 32 + ks) * 2) * 512) + lane;
    dst[0]  = hi;    // part 0
    dst[64] = lo;    // part 1 (+512 shorts)
}

// ---------------------------------------------------------------------------
// Kernel 1: xgT[t][n][b] = b_ih[n]+b_hh[n] + sum_e embed[x[b,t]][e]*W_ih[n][e]
// (unchanged f32 path — keep bisectable)
// ---------------------------------------------------------------------------
__global__ __launch_bounds__(256) void lstm_xgates(
    const int* __restrict__ x,           // [B, T]
    const float* __restrict__ emb,       // [VOCAB, EMBED]
    const float* __restrict__ W_ih,      // [G4, EMBED]
    const float* __restrict__ b_ih,
    const float* __restrict__ b_hh,
    float* __restrict__ xgT)             // [T, G4, B]
{
    const int t   = blockIdx.y;
    const int n0  = blockIdx.x * 64;
    const int tid = threadIdx.x;
    const int ty  = tid >> 4;
    const int tx  = tid & 15;

    __shared__ float As[64][36];
    __shared__ float Bs[64][36];
    __shared__ int   ridx[64];

    if (tid < 64) ridx[tid] = x[tid * SEQ + t];
    __syncthreads();

    float acc[4][4];
#pragma unroll
    for (int i = 0; i < 4; ++i)
#pragma unroll
        for (int j = 0; j < 4; ++j) acc[i][j] = 0.f;

    const int lr = tid >> 2;
    const int lc = (tid & 3) * 8;
    const float* abase = W_ih + (long)(n0 + lr) * EMBED + lc;
    const float* bbase = emb + (long)ridx[lr] * EMBED + lc;

    for (int k0 = 0; k0 < EMBED; k0 += 32) {
        *(float4*)&As[lr][lc]     = *(const float4*)(abase + k0);
        *(float4*)&As[lr][lc + 4] = *(const float4*)(abase + k0 + 4);
        *(float4*)&Bs[lr][lc]     = *(const float4*)(bbase + k0);
        *(float4*)&Bs[lr][lc + 4] = *(const float4*)(bbase + k0 + 4);
        __syncthreads();

#pragma unroll
        for (int kk = 0; kk < 32; kk += 4) {
            float4 av[4], bv[4];
#pragma unroll
            for (int i = 0; i < 4; ++i) av[i] = *(const float4*)&As[ty + 16 * i][kk];
#pragma unroll
            for (int j = 0; j < 4; ++j) bv[j] = *(const float4*)&Bs[tx + 16 * j][kk];
#pragma unroll
            for (int i = 0; i < 4; ++i)
#pragma unroll
                for (int j = 0; j < 4; ++j)
                    acc[i][j] += av[i].x * bv[j].x + av[i].y * bv[j].y
                               + av[i].z * bv[j].z + av[i].w * bv[j].w;
        }
        __syncthreads();
    }

#pragma unroll
    for (int i = 0; i < 4; ++i) {
        const int n = n0 + ty + 16 * i;
        const float bias = b_ih[n] + b_hh[n];
#pragma unroll
        for (int j = 0; j < 4; ++j) {
            const int b = tx + 16 * j;
            xgT[((long)t * G4 + n) * BATCH + b] = acc[i][j] + bias;
        }
    }
}

// ---------------------------------------------------------------------------
// Zero-init c and h(t=0) hi/lo. (ws is poisoned 0xAA before every call.)
// ---------------------------------------------------------------------------
__global__ void lstm_init(float* __restrict__ c,
                          unsigned short* __restrict__ hhi,
                          unsigned short* __restrict__ hlo)
{
    const int i = blockIdx.x * blockDim.x + threadIdx.x;
    if (i < BATCH * HIDDEN) { c[i] = 0.f; hhi[i] = 0; hlo[i] = 0; }
}

// ---------------------------------------------------------------------------
// Kernel 2 (x256): one fused LSTM step — v4: MFMA split-bf16.
//   Block (512 thr, 8 waves) owns 16 rows {g*1024+tile*4+jj} x 64 b.
//   Wave w owns k-eighth (4 MFMA k-steps of 32). Per kstep, per M-tile m
//   (batch 16s): 3 MFMAs (hh*Wh, hl*Wh, hh*Wl). W frags from the
//   fragment-ready global array (coalesced 1KB/instr); h frags from L2
//   (hi/lo bf16 [64][1024]); NO LDS in the K-loop. Split-K reduce via
//   Zs (stride-66 pad), fused gate phase writes c + h hi/lo.
// ---------------------------------------------------------------------------
__global__ __launch_bounds__(512, 1) void lstm_step(
    const unsigned short* __restrict__ Wf,
    const float* __restrict__ xgT_t,            // [4096][64]
    const unsigned short* __restrict__ hHi_in,  // [64][1024]
    const unsigned short* __restrict__ hLo_in,
    unsigned short* __restrict__ hHi_out,
    unsigned short* __restrict__ hLo_out,
    float* __restrict__ c)                      // [(tile*64+b)*4+jj]
{
    const int tile = blockIdx.x;                                // 0..255
    const int tid  = threadIdx.x;
    const int w    = __builtin_amdgcn_readfirstlane(tid >> 6);  // 0..7
    const int lane = tid & 63;
    const int r16  = lane & 15;
    const int g    = lane >> 4;

    __shared__ float Zs[8 * 16 * 66];   // 33.8 KB split-K partials

    const s16x8* Wf8 = (const s16x8*)Wf;
    const s16x8* hh8 = (const s16x8*)hHi_in;    // [64][128] of s16x8
    const s16x8* hl8 = (const s16x8*)hLo_in;

    // ---- W fragments for this wave's 4 k-steps (reused across 4 M-tiles) ----
    s16x8 Whi[4], Wlo[4];
#pragma unroll
    for (int s = 0; s < 4; ++s) {
        const long bi = ((long)(tile * 32 + w * 4 + s) * 2) * 64 + lane;
        Whi[s] = Wf8[bi];
        Wlo[s] = Wf8[bi + 64];
    }

    // ---- gate-phase xg prefetch (waves 0..3, jj=w) ----
    float xgv[4] = {0.f, 0.f, 0.f, 0.f};
    if (w < 4) {
#pragma unroll
        for (int gg = 0; gg < 4; ++gg)
            xgv[gg] = xgT_t[((long)(gg << 10) + (tile << 2) + w) * BATCH + lane];
    }

    f32x4 acc[4];
#pragma unroll
    for (int m = 0; m < 4; ++m) acc[m] = (f32x4){0.f, 0.f, 0.f, 0.f};

    // ---- h fragments, double-buffered; idx (m,s): (m*16+r16)*128+(w*4+s)*4+g
    s16x8 ah[2][4], al[2][4];
#pragma unroll
    for (int m = 0; m < 4; ++m) {
        const int hidx = (m * 16 + r16) * 128 + (w * 4) * 4 + g;
        ah[0][m] = hh8[hidx];
        al[0][m] = hl8[hidx];
    }

#pragma unroll
    for (int s = 0; s < 4; ++s) {
        const int cur = s & 1, nxt = cur ^ 1;
        if (s < 3) {
#pragma unroll
            for (int m = 0; m < 4; ++m) {
                const int hidx = (m * 16 + r16) * 128 + (w * 4 + s + 1) * 4 + g;
                ah[nxt][m] = hh8[hidx];
                al[nxt][m] = hl8[hidx];
            }
        }
#pragma unroll
        for (int m = 0; m < 4; ++m) {
            acc[m] = __builtin_amdgcn_mfma_f32_16x16x32_bf16(ah[cur][m], Whi[s], acc[m], 0, 0, 0);
            acc[m] = __builtin_amdgcn_mfma_f32_16x16x32_bf16(al[cur][m], Whi[s], acc[m], 0, 0, 0);
            acc[m] = __builtin_amdgcn_mfma_f32_16x16x32_bf16(ah[cur][m], Wlo[s], acc[m], 0, 0, 0);
        }
    }

    // ---- split-K partials: D layout col(r)=lane&15, row(b-in-tile)=g*4+q ----
#pragma unroll
    for (int m = 0; m < 4; ++m)
#pragma unroll
        for (int q = 0; q < 4; ++q) {
            const int b = m * 16 + g * 4 + q;
            Zs[(w * 16 + r16) * 66 + b] = acc[m][q];
        }
    __syncthreads();

    // ---- fused gate phase: wave w<4 handles jj=w, lane=b ----
    if (w < 4) {
        const int jj = w;
        const int b  = lane;
        float z[4];
#pragma unroll
        for (int gg = 0; gg < 4; ++gg) {
            float sum = xgv[gg];
#pragma unroll
            for (int wp = 0; wp < 8; ++wp)
                sum += Zs[(wp * 16 + gg * 4 + jj) * 66 + b];
            z[gg] = sum;
        }
        const float ig = 1.f / (1.f + __expf(-z[0]));
        const float fg = 1.f / (1.f + __expf(-z[1]));
        const float gt = tanhf(z[2]);
        const float og = 1.f / (1.f + __expf(-z[3]));
        float* cp = c + (tile * 64 + b) * 4 + jj;
        const float cn = fg * (*cp) + ig * gt;
        *cp = cn;
        const float hn = og * tanhf(cn);
        const unsigned short hhi = f2bf(hn);
        const unsigned short hlo = f2bf(hn - bf2f(hhi));
        hHi_out[b * HIDDEN + tile * 4 + jj] = hhi;
        hLo_out[b * HIDDEN + tile * 4 + jj] = hlo;
    }
}

// ---------------------------------------------------------------------------
// Kernel 3: out[b][v] = fc_b[v] + sum_k h[b][k] * fc_W[v][k]
// h reconstructed from hi/lo bf16 ([64][1024] each).
// ---------------------------------------------------------------------------
__global__ __launch_bounds__(256) void lstm_fc(
    const unsigned short* __restrict__ h_hi,   // [64][1024]
    const unsigned short* __restrict__ h_lo,
    const float* __restrict__ fc_W,            // [VOCAB, H]
    const float* __restrict__ fc_b,
    float* __restrict__ out)                   // [B, VOCAB]
{
    const int v0  = blockIdx.x * 64;
    const int tid = threadIdx.x;
    const int ty  = tid >> 4;
    const int tx  = tid & 15;

    __shared__ float Hs[64][36];
    __shared__ float Ws[64][36];

    float acc[4][4];
#pragma unroll
    for (int i = 0; i < 4; ++i)
#pragma unroll
        for (int j = 0; j < 4; ++j) acc[i][j] = 0.f;

    const int lr = tid >> 2;          // b
    const int lc = (tid & 3) * 8;     // k offset in 32-chunk
    const s16x8* hi8 = (const s16x8*)h_hi;   // [64][128]
    const s16x8* lo8 = (const s16x8*)h_lo;
    const float* wbase = fc_W + (long)(v0 + lr) * HIDDEN + lc;

    for (int k0 = 0; k0 < HIDDEN; k0 += 32) {
        const int hidx = lr * 128 + ((k0 + lc) >> 3);
        const s16x8 vh = hi8[hidx];
        const s16x8 vl = lo8[hidx];
#pragma unroll
        for (int e = 0; e < 8; ++e)
            Hs[lr][lc + e] = bf2f((unsigned short)vh[e]) + bf2f((unsigned short)vl[e]);
        *(float4*)&Ws[lr][lc]     = *(const float4*)(wbase + k0);
        *(float4*)&Ws[lr][lc + 4] = *(const float4*)(wbase + k0 + 4);
        __syncthreads();

#pragma unroll
        for (int kk = 0; kk < 32; kk += 4) {
            float4 hv[4], wv[4];
#pragma unroll
            for (int i = 0; i < 4; ++i) hv[i] = *(const float4*)&Hs[ty + 16 * i][kk];
#pragma unroll
            for (int j = 0; j < 4; ++j) wv[j] = *(const float4*)&Ws[tx + 16 * j][kk];
#pragma unroll
            for (int i = 0; i < 4; ++i)
#pragma unroll
                for (int j = 0; j < 4; ++j)
                    acc[i][j] += hv[i].x * wv[j].x + hv[i].y * wv[j].y
                               + hv[i].z * wv[j].z + hv[i].w * wv[j].w;
        }
        __syncthreads();
    }

#pragma unroll
    for (int j = 0; j < 4; ++j) {
        const int v = v0 + tx + 16 * j;
        const float bias = fc_b[v];
#pragma unroll
        for (int i = 0; i < 4; ++i) {
            const int b = ty + 16 * i;
            out[(long)b * VOCAB + v] = acc[i][j] + bias;
        }
    }
}

// ---------------------------------------------------------------------------
extern "C" void kernel_launch(void* const* d_in, const int* in_sizes, int n_in,
                              void* d_out, int out_size, void* d_ws, size_t ws_size,
                              hipStream_t stream)
{
    const int*   x     = (const int*)d_in[0];
    const float* emb   = (const float*)d_in[1];
    const float* W_ih  = (const float*)d_in[2];
    const float* W_hh  = (const float*)d_in[3];
    const float* b_ih  = (const float*)d_in[4];
    const float* b_hh  = (const float*)d_in[5];
    const float* fc_W  = (const float*)d_in[6];
    const float* fc_b  = (const float*)d_in[7];
    float* out = (float*)d_out;

    // ws layout: xgT f32 [T][4H][B] (268 MB) | Wf u16 (16 MB)
    //          | hHiA hLoA hHiB hLoB u16 (4x128 KB) | c f32 (256 KB)
    float* xgT = (float*)d_ws;
    unsigned short* Wf   = (unsigned short*)(xgT + (long)SEQ * G4 * BATCH);
    unsigned short* hHiA = Wf + (long)256 * 32 * 2 * 512;
    unsigned short* hLoA = hHiA + BATCH * HIDDEN;
    unsigned short* hHiB = hLoA + BATCH * HIDDEN;
    unsigned short* hLoB = hHiB + BATCH * HIDDEN;
    float* c = (float*)(hLoB + BATCH * HIDDEN);

    lstm_wprep<<<dim3(256, 8), 256, 0, stream>>>(W_hh, Wf);
    lstm_xgates<<<dim3(G4 / 64, SEQ), 256, 0, stream>>>(x, emb, W_ih, b_ih, b_hh, xgT);
    lstm_init<<<dim3(BATCH * HIDDEN / 256), 256, 0, stream>>>(c, hHiA, hLoA);

    unsigned short* hhi[2] = {hHiA, hHiB};
    unsigned short* hlo[2] = {hLoA, hLoB};
    for (int t = 0; t < SEQ; ++t) {
        lstm_step<<<dim3(HIDDEN / 4), 512, 0, stream>>>(
            Wf, xgT + (long)t * G4 * BATCH,
            hhi[t & 1], hlo[t & 1], hhi[(t + 1) & 1], hlo[(t + 1) & 1], c);
    }
    // T even -> final h in A buffers
    lstm_fc<<<dim3(VOCAB / 64), 256, 0, stream>>>(hHiA, hLoA, fc_W, fc_b, out);
}